// Round 15
// baseline (2675.896 us; speedup 1.0000x reference)
//
#include <hip/hip_runtime.h>
#include <cstdint>
#include <cstddef>
#include <cmath>

#define NLAYER 6
#define NH 12
#define DMODEL 384
#define DHEAD 32
#define DFFN 1536
#define BATCH 64
#define SEQ 512
#define NROWS (BATCH*SEQ)   // 32768
#define DQKV 1152           // fused q|k|v row length

typedef unsigned short ushort;
typedef __attribute__((ext_vector_type(8))) short bf16x8;   // 8 bf16 = 4 VGPRs
typedef __attribute__((ext_vector_type(4))) float f32x4;

// ---------------------------------------------------------------- utilities

__device__ inline float bf2f(ushort u) {
    union { unsigned int i; float f; } c; c.i = ((unsigned int)u) << 16; return c.f;
}
__device__ inline ushort f2bf(float f) {
    union { float f; unsigned int i; } c; c.f = f;
    unsigned int i = c.i;
    unsigned int lsb = (i >> 16) & 1u;
    i += 0x7fffu + lsb;          // round-to-nearest-even
    return (ushort)(i >> 16);
}

__device__ inline float wave_reduce_sum(float v) {
    #pragma unroll
    for (int m = 32; m >= 1; m >>= 1) v += __shfl_xor(v, m, 64);
    return v;
}

__device__ inline float sigmoidf(float x) { return 1.0f / (1.0f + expf(-x)); }

// fast exp-based tanh-gelu (R12 win): tanh(y) = 1 - 2/(e^{2y}+1); ~8 VALU ops.
__device__ inline float gelu_tanh(float x) {
    const float c = 0.7978845608028654f; // sqrt(2/pi)
    float y = c * (x + 0.044715f * x * x * x);
    float e = __expf(2.0f * y);
    float t = 1.0f - 2.0f * __builtin_amdgcn_rcpf(e + 1.0f);
    return 0.5f * x * (1.0f + t);
}

// async global->LDS, 16 bytes per lane; lds base must be wave-uniform
__device__ inline void async16(const ushort* g, ushort* l) {
    __builtin_amdgcn_global_load_lds(
        (const __attribute__((address_space(1))) unsigned int*)g,
        (__attribute__((address_space(3))) unsigned int*)l,
        16, 0, 0);
}

// dot of two float2[16] register arrays -> scalar (4 chains + tree)
__device__ inline float dot16(const float2* a, const float2* b) {
    float2 s0 = a[0]*b[0], s1 = a[1]*b[1], s2 = a[2]*b[2], s3 = a[3]*b[3];
    #pragma unroll
    for (int j = 4; j < 16; j += 4) {
        s0 += a[j]*b[j]; s1 += a[j+1]*b[j+1]; s2 += a[j+2]*b[j+2]; s3 += a[j+3]*b[j+3];
    }
    float2 s = (s0 + s1) + (s2 + s3);
    return s.x + s.y;
}

// ---------------------------------------------------------------- weight convert+transpose
__global__ __launch_bounds__(256)
void convT_kernel(const float* __restrict__ W, ushort* __restrict__ WT, int K, int N,
                  size_t lStride, int nOff)
{
    __shared__ float t[32][33];
    int k0 = blockIdx.x * 32, n0 = blockIdx.y * 32, L = blockIdx.z;
    const float* Wl = W + (size_t)L * K * N;
    ushort* WTl = WT + (size_t)L * lStride;
    int tx = threadIdx.x & 31, ty = threadIdx.x >> 5;   // 32 x 8
    #pragma unroll
    for (int i = 0; i < 4; ++i)
        t[ty + 8 * i][tx] = Wl[(size_t)(k0 + ty + 8 * i) * N + n0 + tx];
    __syncthreads();
    #pragma unroll
    for (int i = 0; i < 4; ++i)
        WTl[(size_t)(nOff + n0 + ty + 8 * i) * K + k0 + tx] = f2bf(t[tx][ty + 8 * i]);
}

// ---------------------------------------------------------------- fused qkv bias concat: [L][1152]
__global__ __launch_bounds__(384)
void biascat_kernel(const float* __restrict__ bq, const float* __restrict__ bk,
                    const float* __restrict__ bv, float* __restrict__ dst)
{
    int L = blockIdx.x, d = threadIdx.x;
    dst[(size_t)L * DQKV + d]             = bq[(size_t)L * DMODEL + d];
    dst[(size_t)L * DQKV + DMODEL + d]    = bk[(size_t)L * DMODEL + d];
    dst[(size_t)L * DQKV + 2*DMODEL + d]  = bv[(size_t)L * DMODEL + d];
}

// ---------------------------------------------------------------- embedding + LN (writes fp32 x and bf16 xb)
__global__ __launch_bounds__(256)
void embed_ln_kernel(const int* __restrict__ ids, const float* __restrict__ we,
                     const float* __restrict__ pe, const float* __restrict__ te,
                     const float* __restrict__ g, const float* __restrict__ bb,
                     float* __restrict__ x, ushort* __restrict__ xb)
{
    int row = blockIdx.x * 4 + (threadIdx.x >> 6);
    int lane = threadIdx.x & 63;
    int l = row & (SEQ - 1);
    int id = ids[row];
    float vals[6];
    float s = 0.f;
    #pragma unroll
    for (int t = 0; t < 6; ++t) {
        int d = lane + 64 * t;
        float v = we[(size_t)id * DMODEL + d] + pe[(size_t)l * DMODEL + d] + te[d];
        vals[t] = v; s += v;
    }
    s = wave_reduce_sum(s);
    float m = s * (1.0f / DMODEL);
    float s2 = 0.f;
    #pragma unroll
    for (int t = 0; t < 6; ++t) { float dd = vals[t] - m; s2 += dd * dd; }
    s2 = wave_reduce_sum(s2);
    float rs = rsqrtf(s2 * (1.0f / DMODEL) + 1e-12f);
    #pragma unroll
    for (int t = 0; t < 6; ++t) {
        int d = lane + 64 * t;
        float val = (vals[t] - m) * rs * g[d] + bb[d];
        x[(size_t)row * DMODEL + d] = val;
        xb[(size_t)row * DMODEL + d] = f2bf(val);
    }
}

// ---------------------------------------------------------------- residual add + LN (separate residual buffer r)
__global__ __launch_bounds__(256)
void add_ln_kernel(float* x, ushort* __restrict__ xb, const ushort* __restrict__ r,
                   const float* __restrict__ g, const float* __restrict__ bb)
{
    int row = blockIdx.x * 4 + (threadIdx.x >> 6);
    int lane = threadIdx.x & 63;
    float vals[6];
    float s = 0.f;
    #pragma unroll
    for (int t = 0; t < 6; ++t) {
        int d = lane + 64 * t;
        size_t idx = (size_t)row * DMODEL + d;
        float v = x[idx] + bf2f(r[idx]);
        vals[t] = v; s += v;
    }
    s = wave_reduce_sum(s);
    float m = s * (1.0f / DMODEL);
    float s2 = 0.f;
    #pragma unroll
    for (int t = 0; t < 6; ++t) { float dd = vals[t] - m; s2 += dd * dd; }
    s2 = wave_reduce_sum(s2);
    float rs = rsqrtf(s2 * (1.0f / DMODEL) + 1e-12f);
    #pragma unroll
    for (int t = 0; t < 6; ++t) {
        int d = lane + 64 * t;
        size_t idx = (size_t)row * DMODEL + d;
        float val = (vals[t] - m) * rs * g[d] + bb[d];
        x[idx] = val;
        xb[idx] = f2bf(val);
    }
}

// ---------------------------------------------------------------- residual add + LN, residual IN xb (in place)
__global__ __launch_bounds__(256)
void add_ln_ip_kernel(float* x, ushort* xb,
                      const float* __restrict__ g, const float* __restrict__ bb)
{
    int row = blockIdx.x * 4 + (threadIdx.x >> 6);
    int lane = threadIdx.x & 63;
    float vals[6];
    float s = 0.f;
    #pragma unroll
    for (int t = 0; t < 6; ++t) {
        int d = lane + 64 * t;
        size_t idx = (size_t)row * DMODEL + d;
        float v = x[idx] + bf2f(xb[idx]);
        vals[t] = v; s += v;
    }
    s = wave_reduce_sum(s);
    float m = s * (1.0f / DMODEL);
    float s2 = 0.f;
    #pragma unroll
    for (int t = 0; t < 6; ++t) { float dd = vals[t] - m; s2 += dd * dd; }
    s2 = wave_reduce_sum(s2);
    float rs = rsqrtf(s2 * (1.0f / DMODEL) + 1e-12f);
    #pragma unroll
    for (int t = 0; t < 6; ++t) {
        int d = lane + 64 * t;
        size_t idx = (size_t)row * DMODEL + d;
        float val = (vals[t] - m) * rs * g[d] + bb[d];
        x[idx] = val;
        xb[idx] = f2bf(val);
    }
}

// ---------------------------------------------------------------- bf16 MFMA GEMM, async-staged [verified R7]
// R12 win: XCD-chunked A-major block swizzle (identity fallback nwg%8!=0).
template<typename TC>
__global__ __launch_bounds__(256)
void gemm_mfma(const ushort* __restrict__ A, const ushort* __restrict__ WT,
               const float* __restrict__ bias, TC* __restrict__ C,
               int M, int N, int K, int Astride, int act)
{
    __shared__ __align__(16) ushort As[128 * 64];   // 16 KB
    __shared__ __align__(16) ushort Bs[128 * 64];   // 16 KB
    int tid = threadIdx.x;
    int lane = tid & 63, wv = tid >> 6;
    int waveM = wv >> 1, waveN = wv & 1;
    int lm = lane & 15, quad = lane >> 4;

    int bid = blockIdx.x + gridDim.x * blockIdx.y;
    int nwg = gridDim.x * gridDim.y;
    int w = bid;
    if ((nwg & 7) == 0) {
        int cpx = nwg >> 3;
        w = (bid & 7) * cpx + (bid >> 3);
    }
    int xt = w / gridDim.y;      // row-tile (A-major ordering)
    int yt = w % gridDim.y;      // col-tile
    int row0 = xt * 128, col0 = yt * 128;

    int srow = lane >> 3, sseg = lane & 7;          // staging: 8 rows x 8 segs

    f32x4 acc[4][4] = {};

    for (int k0 = 0; k0 < K; k0 += 64) {
        __syncthreads();
        #pragma unroll
        for (int i = 0; i < 4; ++i) {
            int r = wv * 32 + i * 8 + srow;
            int sg = sseg ^ (r & 7);
            async16(A  + (size_t)(row0 + r) * Astride + k0 + sg * 8, &As[(wv * 32 + i * 8) * 64]);
            async16(WT + (size_t)(col0 + r) * K + k0 + sg * 8, &Bs[(wv * 32 + i * 8) * 64]);
        }
        __syncthreads();

        #pragma unroll
        for (int ks = 0; ks < 2; ++ks) {
            int physA = ((ks * 4 + quad) ^ (lm & 7)) * 8;
            bf16x8 af[4], bf[4];
            #pragma unroll
            for (int mt = 0; mt < 4; ++mt)
                af[mt] = *(const bf16x8*)&As[(waveM * 64 + mt * 16 + lm) * 64 + physA];
            #pragma unroll
            for (int nt = 0; nt < 4; ++nt)
                bf[nt] = *(const bf16x8*)&Bs[(waveN * 64 + nt * 16 + lm) * 64 + physA];
            #pragma unroll
            for (int mt = 0; mt < 4; ++mt)
                #pragma unroll
                for (int nt = 0; nt < 4; ++nt)
                    acc[mt][nt] = __builtin_amdgcn_mfma_f32_16x16x32_bf16(af[mt], bf[nt], acc[mt][nt], 0, 0, 0);
        }
    }

    #pragma unroll
    for (int mt = 0; mt < 4; ++mt) {
        #pragma unroll
        for (int nt = 0; nt < 4; ++nt) {
            int col = col0 + waveN * 64 + nt * 16 + lm;
            float bv = bias[col];
            #pragma unroll
            for (int r = 0; r < 4; ++r) {
                int row = row0 + waveM * 64 + mt * 16 + quad * 4 + r;
                float val = acc[mt][nt][r] + bv;
                if (act == 1) val = gelu_tanh(gelu_tanh(val));
                if constexpr (sizeof(TC) == 2)
                    C[(size_t)row * N + col] = f2bf(val);
                else
                    C[(size_t)row * N + col] = val;
            }
        }
    }
}

// ---------------------------------------------------------------- beta: wave per row, coalesced bf16 x  [verified R7]
__global__ __launch_bounds__(256)
void beta_kernel(const ushort* __restrict__ xb, const float* __restrict__ Wb,
                 const float* __restrict__ mask, float* __restrict__ beta)
{
    int row = blockIdx.x * 4 + (threadIdx.x >> 6);
    int lane = threadIdx.x & 63;
    float xr[6];
    #pragma unroll
    for (int t = 0; t < 6; ++t) xr[t] = bf2f(xb[(size_t)row * DMODEL + lane + 64 * t]);
    float mine = 0.f;
    #pragma unroll
    for (int h = 0; h < NH; ++h) {
        float p = 0.f;
        #pragma unroll
        for (int t = 0; t < 6; ++t) p += xr[t] * Wb[(size_t)(lane + 64 * t) * NH + h];
        p = wave_reduce_sum(p);
        if (lane == h) mine = p;
    }
    if (lane < NH) beta[(size_t)row * NH + lane] = sigmoidf(mine) * mask[row];
}

// ---------------------------------------------------------------- delta-rule scan v13: v12 + sched_group_barrier read clustering
// v12 (155 us): 727 cyc/step, issue ~265, stall ~460. Hypothesis: hipcc sinks
// the 18 per-step ds_reads to just-before-use inside the dot chains, exposing
// ~8x60 cyc of serialized LDS latency. v13 pins the schedule per step with
// T19 sched_group_barrier: cluster all 18 DS_READs first (latencies pipeline;
// one ~120cyc wait), then the VALU block, then the single DS_WRITE.
// Compile-time directive only -- zero semantic change vs v12.
#define SCAN_T 32
#define SPAD 36
__global__ __launch_bounds__(64)
void scan_kernel(const ushort* __restrict__ qkv, const float* __restrict__ beta,
                 const float* __restrict__ mask,
                 const float* __restrict__ dfast, const float* __restrict__ dslow,
                 ushort* __restrict__ o)
{
    __shared__ __align__(16) float qs[SCAN_T][SPAD];
    __shared__ __align__(16) float ks[SCAN_T][SPAD];
    __shared__ __align__(16) float vs[SCAN_T][SPAD];
    __shared__ float bs[SCAN_T];
    __shared__ float osb2[SCAN_T][64];   // per-tile o halves (8 KB)

    int bh = blockIdx.x;               // 768 blocks, one (b,h) each
    int lane = threadIdx.x;
    int half = lane >> 5, n = lane & 31;
    int h16 = half << 4;
    int myb = bh / NH, myh = bh % NH;

    float g = sigmoidf(half ? dslow[myh] : dfast[myh]);
    float2 g2 = make_float2(g, g);
    float2 S[16];
    #pragma unroll
    for (int j = 0; j < 16; ++j) S[j] = make_float2(0.f, 0.f);

    // prefetch regs: lane (half,n) stages 16 elements (offset h16) of row t0+n
    uint4 pq[2], pk[2], pv[2];
    float pb, pmk;
    {
        size_t ra = (size_t)(myb * SEQ + n) * DQKV + myh * DHEAD + h16;
        pq[0] = *(const uint4*)(qkv + ra);     pq[1] = *(const uint4*)(qkv + ra + 8);
        pk[0] = *(const uint4*)(qkv + ra + DMODEL);     pk[1] = *(const uint4*)(qkv + ra + DMODEL + 8);
        pv[0] = *(const uint4*)(qkv + ra + 2*DMODEL);   pv[1] = *(const uint4*)(qkv + ra + 2*DMODEL + 8);
        pb  = beta[(size_t)(myb * SEQ + n) * NH + myh];
        pmk = mask[myb * SEQ + n];
    }

    for (int t0 = 0; t0 < SEQ; t0 += SCAN_T) {
        __syncthreads();
        // ---- stage tile: fused q/k l2norm (cross-half shfl once) + k*mask
        {
            ushort tq[16], tk[16], tv[16];
            *(uint4*)tq = pq[0]; *(uint4*)(tq + 8) = pq[1];
            *(uint4*)tk = pk[0]; *(uint4*)(tk + 8) = pk[1];
            *(uint4*)tv = pv[0]; *(uint4*)(tv + 8) = pv[1];
            float qv[16], kv[16];
            float sq = 0.f, sk = 0.f;
            #pragma unroll
            for (int j = 0; j < 16; ++j) {
                qv[j] = bf2f(tq[j]); sq += qv[j] * qv[j];
                kv[j] = bf2f(tk[j]); sk += kv[j] * kv[j];
            }
            sq += __shfl_xor(sq, 32, 64);   // partner lane = other half of same row
            sk += __shfl_xor(sk, 32, 64);
            float rq = 1.0f / (sqrtf(sq) + 1e-6f);
            float rk = pmk / (sqrtf(sk) + 1e-6f);
            #pragma unroll
            for (int s2 = 0; s2 < 4; ++s2) {
                float4 fq, fk, fv;
                fq.x = qv[s2*4+0]*rq; fq.y = qv[s2*4+1]*rq; fq.z = qv[s2*4+2]*rq; fq.w = qv[s2*4+3]*rq;
                fk.x = kv[s2*4+0]*rk; fk.y = kv[s2*4+1]*rk; fk.z = kv[s2*4+2]*rk; fk.w = kv[s2*4+3]*rk;
                fv.x = bf2f(tv[s2*4+0]); fv.y = bf2f(tv[s2*4+1]); fv.z = bf2f(tv[s2*4+2]); fv.w = bf2f(tv[s2*4+3]);
                *(float4*)&qs[n][h16 + s2*4] = fq;
                *(float4*)&ks[n][h16 + s2*4] = fk;
                *(float4*)&vs[n][h16 + s2*4] = fv;
            }
            if (!half) bs[n] = pb;
        }
        __syncthreads();

        // ---- prefetch next tile (vmcnt only; rows >= t0+32, o-writes < t0+32)
        if (t0 + SCAN_T < SEQ) {
            size_t ra = (size_t)(myb * SEQ + t0 + SCAN_T + n) * DQKV + myh * DHEAD + h16;
            pq[0] = *(const uint4*)(qkv + ra);     pq[1] = *(const uint4*)(qkv + ra + 8);
            pk[0] = *(const uint4*)(qkv + ra + DMODEL);     pk[1] = *(const uint4*)(qkv + ra + DMODEL + 8);
            pv[0] = *(const uint4*)(qkv + ra + 2*DMODEL);   pv[1] = *(const uint4*)(qkv + ra + 2*DMODEL + 8);
            pb  = beta[(size_t)(myb * SEQ + t0 + SCAN_T + n) * NH + myh];
            pmk = mask[myb * SEQ + t0 + SCAN_T + n];
        }

        #pragma unroll 4
        for (int t = 0; t < SCAN_T; ++t) {
            float2 kt[16], qt[16];
            #pragma unroll
            for (int s2 = 0; s2 < 8; ++s2) {
                *(float4*)&kt[s2 * 2] = *(const float4*)&ks[t][s2 * 4];   // full row: broadcast
                *(float4*)&qt[s2 * 2] = *(const float4*)&qs[t][s2 * 4];
            }
            float vt = vs[t][n], bt = bs[t];
            // pin schedule: 18 DS_READs cluster first (latencies pipeline),
            // then the VALU block, then the single DS_WRITE.
            __builtin_amdgcn_sched_group_barrier(0x100, 18, 0);  // DS_READ x18
            __builtin_amdgcn_sched_group_barrier(0x002, 90, 0);  // VALU block

            float p = dot16(kt, S);
            float c = bt * (vt - p);
            float2 c2 = make_float2(c, c);

            float2 o0 = make_float2(0.f, 0.f), o1 = o0, o2 = o0, o3 = o0;
            #pragma unroll
            for (int j = 0; j < 16; j += 4) {
                S[j]   = g2 * S[j]   + kt[j]   * c2;
                S[j+1] = g2 * S[j+1] + kt[j+1] * c2;
                S[j+2] = g2 * S[j+2] + kt[j+2] * c2;
                S[j+3] = g2 * S[j+3] + kt[j+3] * c2;
                o0 += qt[j]   * S[j];
                o1 += qt[j+1] * S[j+1];
                o2 += qt[j+2] * S[j+2];
                o3 += qt[j+3] * S[j+3];
            }
            float2 ov = (o0 + o1) + (o2 + o3);
            osb2[t][lane] = ov.x + ov.y;     // fire-and-forget; combined in bulk phase
            __builtin_amdgcn_sched_group_barrier(0x200, 1, 0);   // DS_WRITE x1
        }

        // ---- bulk o-combine + store (pipelined; off the recurrence path)
        #pragma unroll
        for (int tt = 0; tt < SCAN_T / 2; ++tt) {
            int t = tt * 2 + half;
            float osum = osb2[t][n] + osb2[t][n + 32];
            o[((size_t)(myb * SEQ + t0 + t)) * DQKV + myh * DHEAD + n] = f2bf(0.5f * osum);
        }
    }
}

// ---------------------------------------------------------------- masked mean-pool + l2 normalize
__global__ __launch_bounds__(384)
void pool_kernel(const float* __restrict__ x, const float* __restrict__ mask,
                 float* __restrict__ out)
{
    int b = blockIdx.x;
    int d = threadIdx.x;
    float acc = 0.f, msum = 0.f;
    for (int l = 0; l < SEQ; ++l) {
        float mk = mask[b * SEQ + l];
        acc += x[((size_t)b * SEQ + l) * DMODEL + d] * mk;
        msum += mk;
    }
    float emb = acc / fmaxf(msum, 1e-9f);
    __shared__ float red[6];
    float ss = wave_reduce_sum(emb * emb);
    int wvi = d >> 6, ln = d & 63;
    if (ln == 0) red[wvi] = ss;
    __syncthreads();
    float tot = 0.f;
    #pragma unroll
    for (int i = 0; i < 6; ++i) tot += red[i];
    float nrm = fmaxf(sqrtf(tot), 1e-12f);
    out[(size_t)b * DMODEL + d] = emb / nrm;
}

// ---------------------------------------------------------------- launch

extern "C" void kernel_launch(void* const* d_in, const int* in_sizes, int n_in,
                              void* d_out, int out_size, void* d_ws, size_t ws_size,
                              hipStream_t stream)
{
    const int*   ids   = (const int*)d_in[0];
    const float* mask  = (const float*)d_in[1];
    const float* we    = (const float*)d_in[2];
    const float* pe    = (const float*)d_in[3];
    const float* te    = (const float*)d_in[4];
    const float* elg   = (const float*)d_in[5];
    const float* elb   = (const float*)d_in[6];
    const float* Wq    = (const float*)d_in[7];
    const float* bq    = (const float*)d_in[8];
    const float* Wk    = (const float*)d_in[9];
    const float* bk    = (const float*)d_in[10];
    const float* Wv    = (const float*)d_in[11];
    const float* bv    = (const float*)d_in[12];
    const float* Wb    = (const float*)d_in[13];
    const float* dfast = (const float*)d_in[14];
    const float* dslow = (const float*)d_in[15];
    const float* Wo    = (const float*)d_in[16];
    const float* bo    = (const float*)d_in[17];
    const float* l1g   = (const float*)d_in[18];
    const float* l1b   = (const float*)d_in[19];
    const float* W1    = (const float*)d_in[20];
    const float* b1    = (const float*)d_in[21];
    const float* W2    = (const float*)d_in[22];
    const float* b2    = (const float*)d_in[23];
    const float* l2g   = (const float*)d_in[24];
    const float* l2b   = (const float*)d_in[25];
    float* out = (float*)d_out;

    // ---- workspace: 199.0 MB total (proven ceiling 202.9 MB, R4) ----
    const size_t RD = (size_t)NROWS * DMODEL;    // 12,582,912 elements
    float* x      = (float*)d_ws;                      // 50.33 MB
    float* betab  = x + RD;                            //  1.57 MB
    ushort* xb    = (ushort*)(betab + (size_t)NROWS * NH);   // 25.17 MB
    ushort* qkvb  = xb + RD;                           // 75.50 MB  [row][1152]
    ushort* ab    = qkvb + (size_t)NROWS * DQKV;       // 25.17 MB (attn out; FFN: tail of h)
    ushort* WqkvT = ab + RD;                           //  5.31 MB [L][1152][384]
    ushort* WoT   = WqkvT + (size_t)NLAYER * DQKV * DMODEL;  // 1.77 MB
    ushort* W1T   = WoT + (size_t)NLAYER * DMODEL * DMODEL;  // 7.08 MB [L][1536][384]
    ushort* W2T   = W1T + (size_t)NLAYER * DMODEL * DFFN;    // 7.08 MB [L][384][1536]
    float* biasqkv = (float*)(W2T + (size_t)NLAYER * DFFN * DMODEL); // 27 KB

    dim3 blk256(256);
    dim3 rowsGrid(NROWS / 4);
    dim3 gemmGrid_QKV(NROWS / 128, DQKV / 128);      // (256, 9)
    dim3 gemmGrid_D(NROWS / 128, DMODEL / 128);      // (256, 3)
    dim3 gemmGrid_F1(NROWS / 128, DFFN / 128);       // (256, 12) unchunked
    dim3 gemmGrid_F2(NROWS / 128, DMODEL / 128);     // (256, 3)  unchunked
    dim3 scanGrid(BATCH * NH);                       // 768 single-wave blocks (state-split)

    const size_t lsQKV = (size_t)DQKV * DMODEL;
    convT_kernel<<<dim3(12, 12, NLAYER), blk256, 0, stream>>>(Wq, WqkvT, DMODEL, DMODEL, lsQKV, 0);
    convT_kernel<<<dim3(12, 12, NLAYER), blk256, 0, stream>>>(Wk, WqkvT, DMODEL, DMODEL, lsQKV, DMODEL);
    convT_kernel<<<dim3(12, 12, NLAYER), blk256, 0, stream>>>(Wv, WqkvT, DMODEL, DMODEL, lsQKV, 2*DMODEL);
    convT_kernel<<<dim3(12, 12, NLAYER), blk256, 0, stream>>>(Wo, WoT, DMODEL, DMODEL, (size_t)DMODEL*DMODEL, 0);
    convT_kernel<<<dim3(12, 48, NLAYER), blk256, 0, stream>>>(W1, W1T, DMODEL, DFFN, (size_t)DMODEL*DFFN, 0);
    convT_kernel<<<dim3(48, 12, NLAYER), blk256, 0, stream>>>(W2, W2T, DFFN, DMODEL, (size_t)DFFN*DMODEL, 0);
    biascat_kernel<<<dim3(NLAYER), dim3(384), 0, stream>>>(bq, bk, bv, biasqkv);

    embed_ln_kernel<<<rowsGrid, blk256, 0, stream>>>(ids, we, pe, te, elg, elb, x, xb);

    for (int i = 0; i < NLAYER; ++i) {
        const ushort* WqkvT_i = WqkvT + (size_t)i * lsQKV;
        const ushort* WoT_i   = WoT + (size_t)i * DMODEL * DMODEL;
        const float*  Wb_i    = Wb  + (size_t)i * DMODEL * NH;
        const ushort* W1T_i   = W1T + (size_t)i * DMODEL * DFFN;
        const ushort* W2T_i   = W2T + (size_t)i * DFFN * DMODEL;

        gemm_mfma<ushort><<<gemmGrid_QKV, blk256, 0, stream>>>(xb, WqkvT_i, biasqkv + (size_t)i * DQKV,
                                                               qkvb, NROWS, DQKV, DMODEL, DMODEL, 0);
        beta_kernel<<<rowsGrid, blk256, 0, stream>>>(xb, Wb_i, mask, betab);
        // q/k l2norm + k*mask fused into scan staging; o overwrites q-section of qkvb
        scan_kernel<<<scanGrid, dim3(64), 0, stream>>>(qkvb, betab, mask,
                                                       dfast + i * NH, dslow + i * NH, qkvb);
        // Wo GEMM reads strided o (Astride = DQKV)
        gemm_mfma<ushort><<<gemmGrid_D, blk256, 0, stream>>>(qkvb, WoT_i, bo + i * DMODEL, ab,
                                                             NROWS, DMODEL, DMODEL, DQKV, 0);
        add_ln_kernel<<<rowsGrid, blk256, 0, stream>>>(x, xb, ab, l1g + i * DMODEL, l1b + i * DMODEL);

        // FFN UNCHUNKED (R11 win): h spans qkvb+ab (contiguous, exactly
        // 100,663,296 B; both dead). W2-out -> xb (dead after W1 GEMM);
        // add_ln_ip reads residual from xb and rewrites it.
        {
            ushort* hbuf = qkvb;   // 100.66 MB window (qkvb..ab end)
            gemm_mfma<ushort><<<gemmGrid_F1, blk256, 0, stream>>>(xb, W1T_i, b1 + i * DFFN, hbuf,
                                                                  NROWS, DFFN, DMODEL, DMODEL, 1);
            gemm_mfma<ushort><<<gemmGrid_F2, blk256, 0, stream>>>(hbuf, W2T_i, b2 + i * DMODEL, xb,
                                                                  NROWS, DMODEL, DFFN, DFFN, 0);
            add_ln_ip_kernel<<<rowsGrid, blk256, 0, stream>>>(x, xb, l2g + i * DMODEL, l2b + i * DMODEL);
        }
    }

    pool_kernel<<<dim3(BATCH), dim3(384), 0, stream>>>(x, mask, out);
}